// Round 6
// baseline (288.950 us; speedup 1.0000x reference)
//
#include <hip/hip_runtime.h>

#define HORIZON 2048
#define B_TOTAL 4096
#define T_OUT 2047

typedef float v2f __attribute__((ext_vector_type(2)));

// Hardware transcendentals (v_exp_f32 = 2^x, v_rcp_f32 = 1/x, ~1 ulp)
__device__ __forceinline__ float hw_exp2(float x) {
    float r;
    asm("v_exp_f32 %0, %1" : "=v"(r) : "v"(x));
    return r;
}
__device__ __forceinline__ float hw_rcp(float x) {
    float r;
    asm("v_rcp_f32 %0, %1" : "=v"(r) : "v"(x));
    return r;
}

// Forced VOP3P packed fp32 (CDNA2+: full-rate, 2 lanes' work per issue slot)
__device__ __forceinline__ v2f pk_fma(v2f a, v2f b, v2f c) {
    v2f d;
    asm("v_pk_fma_f32 %0, %1, %2, %3" : "=v"(d) : "v"(a), "v"(b), "v"(c));
    return d;
}
__device__ __forceinline__ v2f pk_mul(v2f a, v2f b) {
    v2f d;
    asm("v_pk_mul_f32 %0, %1, %2" : "=v"(d) : "v"(a), "v"(b));
    return d;
}
__device__ __forceinline__ v2f pk_add(v2f a, v2f b) {
    v2f d;
    asm("v_pk_add_f32 %0, %1, %2" : "=v"(d) : "v"(a), "v"(b));
    return d;
}
// clamp to [lo,hi] in one VOP3 (no literals allowed -> operands in regs)
__device__ __forceinline__ float med3(float a, float lo, float hi) {
    float r;
    asm("v_med3_f32 %0, %1, %2, %3" : "=v"(r) : "v"(a), "v"(lo), "v"(hi));
    return r;
}

// DPP-mapped move (VALU pipe); fuses into v_add_f32_dpp
template<int CTRL>
__device__ __forceinline__ float dpp_mov(float v) {
    return __int_as_float(__builtin_amdgcn_update_dpp(
        0, __float_as_int(v), CTRL, 0xF, 0xF, true));
}

// Sum over each 16-lane DPP row; result uniform across the 16 lanes.
__device__ __forceinline__ float rowsum16(float v) {
    v += dpp_mov<0xB1>(v);   // quad_perm xor1
    v += dpp_mov<0x4E>(v);   // quad_perm xor2
    v += dpp_mov<0x124>(v);  // row_ror:4
    v += dpp_mov<0x128>(v);  // row_ror:8
    return v;
}

#define CS -24.04491734814939f   // -log2(e)/0.06: sigmoid(z/tau)=1/(1+2^(CS*z))
#define ACL 4.8f                 // tanh input clamp for the Pade(7,6) rational

__global__ __launch_bounds__(64) void thermostat_scan4(
    const float* __restrict__ d,
    const float* __restrict__ W1,
    const float* __restrict__ b1,
    const float* __restrict__ W2,
    const float* __restrict__ b2,
    float* __restrict__ xs,
    float* __restrict__ us)
{
    const int lane = threadIdx.x;        // 0..63
    const int sub  = lane >> 4;          // batch row within wave (0..3)
    const int pos  = lane & 15;          // lane position within 16-row
    const int grow = blockIdx.x * 4 + sub;

    const float* drow = d + (size_t)grow * HORIZON;
    const float4* dv  = (const float4*)drow;

    // Pade coefficients, packed (loop-invariant registers)
    const v2f C378    = {378.f, 378.f};
    const v2f C17325  = {17325.f, 17325.f};
    const v2f C135135 = {135135.f, 135135.f};
    const v2f C28     = {28.f, 28.f};
    const v2f C3150   = {3150.f, 3150.f};
    const v2f C62370  = {62370.f, 62370.f};
    const float cLo = -ACL, cHi = ACL;

    // Lane owns units j = pos+16k, k=0..3, paired p0:(k=0,1) p1:(k=2,3)
    v2f w10[2], w11[2], b1v[2];
    float w20s[4], w21s[4];
#pragma unroll
    for (int p = 0; p < 2; ++p) {
        int j0 = pos + 32 * p;
        int j1 = j0 + 16;
        w10[p] = v2f{W1[j0], W1[j1]};
        w11[p] = v2f{W1[64 + j0], W1[64 + j1]};
        b1v[p] = v2f{b1[j0], b1[j1]};
        w20s[2 * p]     = W2[2 * j0];
        w20s[2 * p + 1] = W2[2 * j1];
        w21s[2 * p]     = W2[2 * j0 + 1];
        w21s[2 * p + 1] = W2[2 * j1 + 1];
    }
    const float zb0  = b2[0];
    const float zb1c = b2[1] * CS;

    float* xs_p = xs + (size_t)grow * T_OUT + pos;
    float* us_p = us + (size_t)grow * T_OUT + pos;

    float4 c0 = dv[0], c1 = dv[1], c2 = dv[2], c3 = dv[3];
    float4 n0 = dv[4], n1 = dv[5], n2 = dv[6], n3 = dv[7];

    float x = c0.x;                 // x0
    float keep_x = x;
    float keep_u = -zb0;            // (+zb0 at store) = 0

    // db[p] = W1[1,:]*dt + b1 for the CURRENT step, built one step ahead
    v2f db0, db1;
    {
        v2f dt2 = v2f{c0.y, c0.y};
        db0 = pk_fma(dt2, w11[0], b1v[0]);
        db1 = pk_fma(dt2, w11[1], b1v[1]);
    }

    auto step = [&](float dt, float dtn, int slot) {
        // layer-1 pre-activation (dt part precomputed last step)
        v2f x2; x2.x = x; x2.y = x;
        v2f a0 = pk_fma(x2, w10[0], db0);
        v2f a1 = pk_fma(x2, w10[1], db1);
        // clamp each element (v_med3_f32)
        v2f ac0, ac1;
        ac0.x = med3(a0.x, cLo, cHi);
        ac0.y = med3(a0.y, cLo, cHi);
        ac1.x = med3(a1.x, cLo, cHi);
        ac1.y = med3(a1.y, cLo, cHi);
        // tanh via Pade(7,6): tanh(a) = a*num(y)/den(y), y=a^2  -- packed
        v2f y0 = pk_mul(ac0, ac0);
        v2f y1 = pk_mul(ac1, ac1);
        v2f nu0 = pk_fma(pk_fma(pk_add(y0, C378), y0, C17325), y0, C135135);
        v2f nu1 = pk_fma(pk_fma(pk_add(y1, C378), y1, C17325), y1, C135135);
        v2f de0 = pk_fma(pk_fma(pk_fma(y0, C28, C3150), y0, C62370), y0, C135135);
        v2f de1 = pk_fma(pk_fma(pk_fma(y1, C28, C3150), y1, C62370), y1, C135135);
        v2f na0 = pk_mul(nu0, ac0);
        v2f na1 = pk_mul(nu1, ac1);
        // paired reciprocals; rp folded into the dot combine
        float rp0 = hw_rcp(de0.x * de0.y);
        float rp1 = hw_rcp(de1.x * de1.y);
        float s0 = na0.x * de0.y, s1 = na0.y * de0.x;
        float s2 = na1.x * de1.y, s3 = na1.y * de1.x;
        // col 1 (critical path): z1 = rp0*(s0 w + s1 w) + rp1*(s2 w + s3 w)
        float qa1 = fmaf(s1, w21s[1], s0 * w21s[0]);
        float qb1 = fmaf(s3, w21s[3], s2 * w21s[2]);
        float q1  = fmaf(qb1, rp1, qa1 * rp0);
        float z1  = rowsum16(q1);
        // col 0 (off critical path)
        float qa0 = fmaf(s1, w20s[1], s0 * w20s[0]);
        float qb0 = fmaf(s3, w20s[3], s2 * w20s[2]);
        float q0  = fmaf(qb0, rp1, qa0 * rp0);
        float z0  = rowsum16(q0);
        // overlap sigmoid latency with next-step prep
        float xd = fmaf(0.99f, x, -dt);
        v2f dn2; dn2.x = dtn; dn2.y = dtn;
        db0 = pk_fma(dn2, w11[0], b1v[0]);
        db1 = pk_fma(dn2, w11[1], b1v[1]);
        // u_bin = sigmoid(z1full/tau) = 1/(1+2^(CS*z1+zb1c)) -- exact path
        float ub = hw_rcp(1.f + hw_exp2(fmaf(z1, CS, zb1c)));
        x = fmaf(0.4f, ub, xd);
        // stash outputs in the owning lane
        bool k = (pos == slot);
        keep_x = k ? x : keep_x;
        keep_u = k ? z0 : keep_u;
    };

    // ---- chunk 0: steps t=1..15 (slot 0 holds x0 / 0) ----
    {
        float dt16[16] = {c0.x, c0.y, c0.z, c0.w, c1.x, c1.y, c1.z, c1.w,
                          c2.x, c2.y, c2.z, c2.w, c3.x, c3.y, c3.z, c3.w};
#pragma unroll
        for (int s = 1; s < 16; ++s)
            step(dt16[s], (s < 15) ? dt16[s + 1] : n0.x, s);
        xs_p[0] = keep_x;
        us_p[0] = keep_u + zb0;
    }

    // ---- chunks 1..126 (16 steps each), prefetch chunk c+1 ----
    for (int c = 1; c < 127; ++c) {
        c0 = n0; c1 = n1; c2 = n2; c3 = n3;
        n0 = dv[4 * c + 4]; n1 = dv[4 * c + 5];
        n2 = dv[4 * c + 6]; n3 = dv[4 * c + 7];
        float dt16[16] = {c0.x, c0.y, c0.z, c0.w, c1.x, c1.y, c1.z, c1.w,
                          c2.x, c2.y, c2.z, c2.w, c3.x, c3.y, c3.z, c3.w};
#pragma unroll
        for (int s = 0; s < 16; ++s)
            step(dt16[s], (s < 15) ? dt16[s + 1] : n0.x, s);
        xs_p[c * 16] = keep_x;
        us_p[c * 16] = keep_u + zb0;
    }

    // ---- chunk 127: steps t=2032..2046 (15 steps, slots 0..14) ----
    {
        float dt16[16] = {n0.x, n0.y, n0.z, n0.w, n1.x, n1.y, n1.z, n1.w,
                          n2.x, n2.y, n2.z, n2.w, n3.x, n3.y, n3.z, n3.w};
#pragma unroll
        for (int s = 0; s < 15; ++s)
            step(dt16[s], dt16[s + 1], s);
        if (pos < 15) {
            xs_p[127 * 16] = keep_x;
            us_p[127 * 16] = keep_u + zb0;
        }
    }
}

extern "C" void kernel_launch(void* const* d_in, const int* in_sizes, int n_in,
                              void* d_out, int out_size, void* d_ws, size_t ws_size,
                              hipStream_t stream) {
    const float* d  = (const float*)d_in[0];
    const float* W1 = (const float*)d_in[1];
    const float* b1 = (const float*)d_in[2];
    const float* W2 = (const float*)d_in[3];
    const float* b2 = (const float*)d_in[4];
    float* xs = (float*)d_out;
    float* us = xs + (size_t)B_TOTAL * T_OUT;

    dim3 grid(B_TOTAL / 4);   // 1024 waves, 4 batch rows per wave
    thermostat_scan4<<<grid, 64, 0, stream>>>(d, W1, b1, W2, b2, xs, us);
}

// Round 7
// 236.180 us; speedup vs baseline: 1.2234x; 1.2234x over previous
//
#include <hip/hip_runtime.h>

#define HORIZON 2048
#define B_TOTAL 4096
#define T_OUT 2047

// Hardware transcendentals as REAL intrinsics (schedulable, not asm-pinned)
#define EXP2(x) __builtin_amdgcn_exp2f(x)
#define RCP(x)  __builtin_amdgcn_rcpf(x)

// DPP-mapped move (VALU pipe); fuses into v_add_f32_dpp
template<int CTRL>
__device__ __forceinline__ float dpp_mov(float v) {
    return __int_as_float(__builtin_amdgcn_update_dpp(
        0, __float_as_int(v), CTRL, 0xF, 0xF, true));
}

// Interleaved dual 16-lane rowsum: both columns reduced with alternating DPP
// adds (hides DPP RAW hazard; z1 chain not serialized behind z0).
__device__ __forceinline__ void rowsum16x2(float& v1, float& v0) {
    float t1, t0;
    t1 = dpp_mov<0xB1>(v1);  t0 = dpp_mov<0xB1>(v0);  v1 += t1; v0 += t0;
    t1 = dpp_mov<0x4E>(v1);  t0 = dpp_mov<0x4E>(v0);  v1 += t1; v0 += t0;
    t1 = dpp_mov<0x124>(v1); t0 = dpp_mov<0x124>(v0); v1 += t1; v0 += t0;
    t1 = dpp_mov<0x128>(v1); t0 = dpp_mov<0x128>(v0); v1 += t1; v0 += t0;
}

#define K1  2.8853900817779268f    // 2*log2(e): tanh(a) = 1 - 2/(2^(K1*a)+1)
#define CS -24.04491734814939f     // -log2(e)/0.06: sigmoid(z/tau)=1/(1+2^(CS*z))

__global__ __launch_bounds__(64) void thermostat_scan4(
    const float* __restrict__ d,
    const float* __restrict__ W1,
    const float* __restrict__ b1,
    const float* __restrict__ W2,
    const float* __restrict__ b2,
    float* __restrict__ xs,
    float* __restrict__ us)
{
    const int lane = threadIdx.x;        // 0..63
    const int sub  = lane >> 4;          // batch row within wave (0..3)
    const int pos  = lane & 15;          // lane position within 16-row
    const int grow = blockIdx.x * 4 + sub;

    const float* drow = d + (size_t)grow * HORIZON;
    const float4* dv  = (const float4*)drow;

    // Lane owns hidden units j = pos + 16k, k=0..3. Constants folded (r3 form).
    float w10c[4], w11c[4], b1c[4], w20m[4], w21m[4];
    float s20p = 0.f, s21p = 0.f;
#pragma unroll
    for (int k = 0; k < 4; ++k) {
        int j = pos + 16 * k;
        w10c[k] = W1[j] * K1;
        w11c[k] = W1[64 + j] * K1;
        b1c[k]  = b1[j] * K1;
        float a0 = W2[2 * j], a1 = W2[2 * j + 1];
        w20m[k] = -2.f * a0;
        w21m[k] = -2.f * a1;
        s20p += a0;
        s21p += a1;
    }
    // Column sums of W2 (loop-invariant): z = zb + sum_j(-2 r_j w_j)
    float s20 = s20p, s21 = s21p;
    rowsum16x2(s21, s20);
    const float zb0  = s20 + b2[0];
    const float zb1c = (s21 + b2[1]) * CS;

    float* xs_p = xs + (size_t)grow * T_OUT + pos;
    float* us_p = us + (size_t)grow * T_OUT + pos;

    float4 c0 = dv[0], c1 = dv[1], c2 = dv[2], c3 = dv[3];
    float4 n0 = dv[4], n1 = dv[5], n2 = dv[6], n3 = dv[7];

    float x = c0.x;                 // x0
    float keep_x = x;
    float keep_u = -zb0;            // (+zb0 at store) = 0

    // db_k = K1*(W1[1,j]*dt + b1_j) for the CURRENT step, built one step ahead
    float db[4];
#pragma unroll
    for (int k = 0; k < 4; ++k) db[k] = fmaf(c0.y, w11c[k], b1c[k]);

    auto step = [&](float dt, float dtn, int slot) {
        // layer 1 + tanh (dt part prefetched): r_k = 1/(exp2(K1*a_k)+1)
        float e0 = EXP2(fmaf(x, w10c[0], db[0]));
        float e1 = EXP2(fmaf(x, w10c[1], db[1]));
        float e2 = EXP2(fmaf(x, w10c[2], db[2]));
        float e3 = EXP2(fmaf(x, w10c[3], db[3]));
        float r0 = RCP(e0 + 1.f);
        float r1 = RCP(e1 + 1.f);
        float r2 = RCP(e2 + 1.f);
        float r3 = RCP(e3 + 1.f);
        // column partials (z = zb + sum -2 r w), both columns interleaved
        float q1 = fmaf(r1, w21m[1], r0 * w21m[0])
                 + fmaf(r3, w21m[3], r2 * w21m[2]);
        float q0 = fmaf(r1, w20m[1], r0 * w20m[0])
                 + fmaf(r3, w20m[3], r2 * w20m[2]);
        rowsum16x2(q1, q0);                       // z1 critical, z0 rides along
        // sigmoid (critical chain): issue exp ASAP
        float eu = EXP2(fmaf(q1, CS, zb1c));
        // fill exp/rcp latency with next-step prep + state partial
        float xd = fmaf(0.99f, x, -dt);
#pragma unroll
        for (int k = 0; k < 4; ++k) db[k] = fmaf(dtn, w11c[k], b1c[k]);
        float ub = RCP(1.f + eu);
        x = fmaf(0.4f, ub, xd);
        // stash outputs in the owning lane
        bool kk = (pos == slot);
        keep_x = kk ? x : keep_x;
        keep_u = kk ? q0 : keep_u;
    };

    // ---- chunk 0: steps t=1..15 (slot 0 holds x0 / 0) ----
    {
        float dt16[16] = {c0.x, c0.y, c0.z, c0.w, c1.x, c1.y, c1.z, c1.w,
                          c2.x, c2.y, c2.z, c2.w, c3.x, c3.y, c3.z, c3.w};
#pragma unroll
        for (int s = 1; s < 16; ++s)
            step(dt16[s], (s < 15) ? dt16[s + 1] : n0.x, s);
        xs_p[0] = keep_x;
        us_p[0] = keep_u + zb0;
    }

    // ---- chunks 1..126 (16 steps each), prefetch chunk c+1 ----
    for (int c = 1; c < 127; ++c) {
        c0 = n0; c1 = n1; c2 = n2; c3 = n3;
        n0 = dv[4 * c + 4]; n1 = dv[4 * c + 5];
        n2 = dv[4 * c + 6]; n3 = dv[4 * c + 7];
        float dt16[16] = {c0.x, c0.y, c0.z, c0.w, c1.x, c1.y, c1.z, c1.w,
                          c2.x, c2.y, c2.z, c2.w, c3.x, c3.y, c3.z, c3.w};
#pragma unroll
        for (int s = 0; s < 16; ++s)
            step(dt16[s], (s < 15) ? dt16[s + 1] : n0.x, s);
        xs_p[c * 16] = keep_x;
        us_p[c * 16] = keep_u + zb0;
    }

    // ---- chunk 127: steps t=2032..2046 (15 steps, slots 0..14) ----
    {
        float dt16[16] = {n0.x, n0.y, n0.z, n0.w, n1.x, n1.y, n1.z, n1.w,
                          n2.x, n2.y, n2.z, n2.w, n3.x, n3.y, n3.z, n3.w};
#pragma unroll
        for (int s = 0; s < 15; ++s)
            step(dt16[s], dt16[s + 1], s);
        if (pos < 15) {
            xs_p[127 * 16] = keep_x;
            us_p[127 * 16] = keep_u + zb0;
        }
    }
}

extern "C" void kernel_launch(void* const* d_in, const int* in_sizes, int n_in,
                              void* d_out, int out_size, void* d_ws, size_t ws_size,
                              hipStream_t stream) {
    const float* d  = (const float*)d_in[0];
    const float* W1 = (const float*)d_in[1];
    const float* b1 = (const float*)d_in[2];
    const float* W2 = (const float*)d_in[3];
    const float* b2 = (const float*)d_in[4];
    float* xs = (float*)d_out;
    float* us = xs + (size_t)B_TOTAL * T_OUT;

    dim3 grid(B_TOTAL / 4);   // 1024 waves, 4 batch rows per wave, 1 wave/SIMD
    thermostat_scan4<<<grid, 64, 0, stream>>>(d, W1, b1, W2, b2, xs, us);
}